// Round 1
// baseline (24.490 us; speedup 1.0000x reference)
//
#include <hip/hip_runtime.h>
#include <math.h>

#define C_CH    192
#define HW_     1024
#define NPLANE  1536           // 8*192 planes of H*W=1024
#define TOTAL_  1572864        // 8*192*32*32

#define LOG2E   1.4426950408889634f
#define KSOS    28.853900817779268f   /* 2*BETA*log2(e) = 20*log2(e) */
#define INV_D   2.95f                 /* 59/20: inverse spacing of sos_b grid */
#define WIN     8

__device__ __forceinline__ float rcp_f(float v)  { return __builtin_amdgcn_rcpf(v); }
__device__ __forceinline__ float exp2_f(float v) { return __builtin_amdgcn_exp2f(v); }

// tanh(z) = 1 - 2/(1+exp(2z));  saturates correctly for |z| large (exp->0 or inf)
__device__ __forceinline__ float fast_tanh(float z) {
  float e = exp2_f(z * (2.0f * LOG2E));
  return 1.0f - 2.0f * rcp_f(e + 1.0f);
}
// sigmoid(z) = 1/(1+exp(-z))
__device__ __forceinline__ float fast_sigmoid(float z) {
  return rcp_f(1.0f + exp2_f(-z * LOG2E));
}
// precise-enough softplus for once-per-block param transform
__device__ __forceinline__ float softplus_f(float v) {
  return log1pf(expf(v));
}

// s_p layout: [0..8]=sp1 [9..17]=sp2 [18..26]=sp3 [27..29]=sp0 [30..32]=sp4
//             [33..35]=b0 [36..38]=b1 [39..41]=b2 [42..44]=b3 [45]=b4
//             [46..48]=tf0 [49..51]=tf1 [52..54]=tf2 [55..57]=tf3
__device__ __forceinline__ float mlp_path(float v, const float* P) {
  float t, a0, a1, a2, d0, d1, d2;
  t = fmaf(P[27], v, P[33]); a0 = fmaf(P[46], fast_tanh(t), t);
  t = fmaf(P[28], v, P[34]); a1 = fmaf(P[47], fast_tanh(t), t);
  t = fmaf(P[29], v, P[35]); a2 = fmaf(P[48], fast_tanh(t), t);

  t = fmaf(P[2], a2, fmaf(P[1], a1, fmaf(P[0], a0, P[36]))); d0 = fmaf(P[49], fast_tanh(t), t);
  t = fmaf(P[5], a2, fmaf(P[4], a1, fmaf(P[3], a0, P[37]))); d1 = fmaf(P[50], fast_tanh(t), t);
  t = fmaf(P[8], a2, fmaf(P[7], a1, fmaf(P[6], a0, P[38]))); d2 = fmaf(P[51], fast_tanh(t), t);

  t = fmaf(P[11], d2, fmaf(P[10], d1, fmaf(P[9],  d0, P[39]))); a0 = fmaf(P[52], fast_tanh(t), t);
  t = fmaf(P[14], d2, fmaf(P[13], d1, fmaf(P[12], d0, P[40]))); a1 = fmaf(P[53], fast_tanh(t), t);
  t = fmaf(P[17], d2, fmaf(P[16], d1, fmaf(P[15], d0, P[41]))); a2 = fmaf(P[54], fast_tanh(t), t);

  t = fmaf(P[20], a2, fmaf(P[19], a1, fmaf(P[18], a0, P[42]))); d0 = fmaf(P[55], fast_tanh(t), t);
  t = fmaf(P[23], a2, fmaf(P[22], a1, fmaf(P[21], a0, P[43]))); d1 = fmaf(P[56], fast_tanh(t), t);
  t = fmaf(P[26], a2, fmaf(P[25], a1, fmaf(P[24], a0, P[44]))); d2 = fmaf(P[57], fast_tanh(t), t);

  return fmaf(P[32], d2, fmaf(P[31], d1, fmaf(P[30], d0, P[45])));
}

__global__ __launch_bounds__(256)
void eb_sos_kernel(const float* __restrict__ x,
                   const float* __restrict__ sos_w, const float* __restrict__ sos_b,
                   const float* __restrict__ m0, const float* __restrict__ m1,
                   const float* __restrict__ m2, const float* __restrict__ m3,
                   const float* __restrict__ m4,
                   const float* __restrict__ c0, const float* __restrict__ c1,
                   const float* __restrict__ c2, const float* __restrict__ c3,
                   const float* __restrict__ c4,
                   const float* __restrict__ f0, const float* __restrict__ f1,
                   const float* __restrict__ f2, const float* __restrict__ f3,
                   float* __restrict__ out)
{
  __shared__ float s_w[68];    // step weights, zero-padded to 68
  __shared__ float s_kb[68];   // KSOS * b_i, padded
  __shared__ float s_pw[64];   // exclusive prefix sums of w, entries 0..60
  __shared__ float s_p[58];    // per-channel MLP params (reparameterized)

  const int t     = threadIdx.x;
  const int plane = blockIdx.x;          // n*C + c
  const int c     = plane % C_CH;

  // ---- wave 0: SoS tables
  if (t < 68) {
    float w = (t < 60) ? sos_w[t] : 0.0f;
    float b = (t < 60) ? sos_b[t] : 0.0f;
    s_w[t]  = w;
    s_kb[t] = KSOS * b;
  }
  // ---- wave 1: exclusive prefix of w via shuffle scan
  if (t >= 64 && t < 128) {
    int i = t - 64;
    float v = (i < 60) ? sos_w[i] : 0.0f;
    float s = v;
    #pragma unroll
    for (int off = 1; off < 64; off <<= 1) {
      float o = __shfl_up(s, off, 64);
      if (i >= off) s += o;
    }
    if (i <= 60) s_pw[i] = s - v;        // exclusive prefix: sum_{j<i} w_j
  }
  // ---- wave 2: per-channel MLP params
  {
    int p = t - 128;
    if (p >= 0 && p < 58) {
      float val;
      if      (p <  9) val = softplus_f(m1[c*9 +  p      ]);
      else if (p < 18) val = softplus_f(m2[c*9 + (p -  9)]);
      else if (p < 27) val = softplus_f(m3[c*9 + (p - 18)]);
      else if (p < 30) val = softplus_f(m0[c*3 + (p - 27)]);
      else if (p < 33) val = softplus_f(m4[c*3 + (p - 30)]);
      else if (p < 36) val = c0[c*3 + (p - 33)];
      else if (p < 39) val = c1[c*3 + (p - 36)];
      else if (p < 42) val = c2[c*3 + (p - 39)];
      else if (p < 45) val = c3[c*3 + (p - 42)];
      else if (p < 46) val = c4[c];
      else if (p < 49) val = tanhf(f0[c*3 + (p - 46)]);
      else if (p < 52) val = tanhf(f1[c*3 + (p - 49)]);
      else if (p < 55) val = tanhf(f2[c*3 + (p - 52)]);
      else             val = tanhf(f3[c*3 + (p - 55)]);
      s_p[p] = val;
    }
  }
  __syncthreads();

  // params -> registers (constant indices after unroll => stays in VGPRs)
  float P[58];
  #pragma unroll
  for (int i = 0; i < 58; ++i) P[i] = s_p[i];

  const int base = plane * HW_;
  float4 xv = reinterpret_cast<const float4*>(x + base)[t];
  float xs[4] = {xv.x, xv.y, xv.z, xv.w};
  float ys[4], ls[4];

  #pragma unroll
  for (int e = 0; e < 4; ++e) {
    float xx = xs[e];

    // ---- SoS staircase: yq = -10 + sum_i w_i * sigmoid(20*(x-b_i)),
    // windowed: steps with b_i < x-1 saturate to w_i (prefix sum),
    // steps with b_i > x+1 contribute ~0 (< 2e-9 each).
    float kf = ceilf((xx + 9.0f) * INV_D);   // ceil((x - R + 10)/d), R=1
    int k = (int)kf;
    k = max(0, min(60, k));
    float acc = s_pw[k];
    float kx  = KSOS * xx;
    #pragma unroll
    for (int i = 0; i < WIN; ++i) {
      float z = s_kb[k + i] - kx;            // -20*(x-b_i)*log2e
      acc = fmaf(s_w[k + i], rcp_f(1.0f + exp2_f(z)), acc);
    }
    float yq = acc - 10.0f;

    // ---- per-channel MLP on yq -/+ 0.5
    float lo = mlp_path(yq - 0.5f, P);
    float up = mlp_path(yq + 0.5f, P);
    float lu = lo + up;
    float sg = (lu > 0.0f) ? -1.0f : ((lu < 0.0f) ? 1.0f : 0.0f);
    float lik = fabsf(fast_sigmoid(sg * up) - fast_sigmoid(sg * lo));
    ls[e] = fmaxf(lik, 1e-9f);
    ys[e] = yq;
  }

  float4 yh4 = make_float4(ys[0], ys[1], ys[2], ys[3]);
  float4 lk4 = make_float4(ls[0], ls[1], ls[2], ls[3]);
  reinterpret_cast<float4*>(out + base)[t]           = yh4;
  reinterpret_cast<float4*>(out + TOTAL_ + base)[t]  = lk4;
}

extern "C" void kernel_launch(void* const* d_in, const int* in_sizes, int n_in,
                              void* d_out, int out_size, void* d_ws, size_t ws_size,
                              hipStream_t stream) {
  const float* x  = (const float*)d_in[0];
  const float* sw = (const float*)d_in[1];
  const float* sb = (const float*)d_in[2];
  const float *M[5], *B[5], *F[4];

  if (n_in >= 17 && in_sizes[4] == 1728) {
    // reference-signature order: m0..m4, c0..c4, f0..f3
    for (int i = 0; i < 5; ++i) M[i] = (const float*)d_in[3 + i];
    for (int i = 0; i < 5; ++i) B[i] = (const float*)d_in[8 + i];
    for (int i = 0; i < 4; ++i) F[i] = (const float*)d_in[13 + i];
  } else {
    // setup_inputs() dict order: m0,c0,f0, m1,c1,f1, m2,c2,f2, m3,c3,f3, m4,c4
    M[0] = (const float*)d_in[3];  B[0] = (const float*)d_in[4];  F[0] = (const float*)d_in[5];
    M[1] = (const float*)d_in[6];  B[1] = (const float*)d_in[7];  F[1] = (const float*)d_in[8];
    M[2] = (const float*)d_in[9];  B[2] = (const float*)d_in[10]; F[2] = (const float*)d_in[11];
    M[3] = (const float*)d_in[12]; B[3] = (const float*)d_in[13]; F[3] = (const float*)d_in[14];
    M[4] = (const float*)d_in[15]; B[4] = (const float*)d_in[16];
  }

  hipLaunchKernelGGL(eb_sos_kernel, dim3(NPLANE), dim3(256), 0, stream,
                     x, sw, sb,
                     M[0], M[1], M[2], M[3], M[4],
                     B[0], B[1], B[2], B[3], B[4],
                     F[0], F[1], F[2], F[3],
                     (float*)d_out);
}

// Round 2
// 19.429 us; speedup vs baseline: 1.2605x; 1.2605x over previous
//
#include <hip/hip_runtime.h>
#include <math.h>

#define C_CH    192
#define HW_     1024
#define NPLANE  1536           // 8*192 planes of H*W=1024
#define TOTAL_  1572864        // 8*192*32*32

#define LOG2E   1.4426950408889634f
#define KSOS    28.853900817779268f   /* 2*BETA*log2(e) = 20*log2(e) */
#define INV_D   2.95f                 /* 59/20: inverse spacing of sos_b grid */

#define LUT_L   2048
#define LUT_X0  (-12.0f)
#define LUT_H   (24.0f / (LUT_L - 1))
#define LUT_IH  ((LUT_L - 1) / 24.0f)
#define CHUNKS_ 4              // kernel1: blocks per channel
#define EPB_    (LUT_L / CHUNKS_)   // entries per block = 512

__device__ __forceinline__ float rcp_f(float v)  { return __builtin_amdgcn_rcpf(v); }
__device__ __forceinline__ float exp2_f(float v) { return __builtin_amdgcn_exp2f(v); }

__device__ __forceinline__ float fast_tanh(float z) {
  float e = exp2_f(z * (2.0f * LOG2E));
  return 1.0f - 2.0f * rcp_f(e + 1.0f);
}
__device__ __forceinline__ float fast_sigmoid(float z) {
  return rcp_f(1.0f + exp2_f(-z * LOG2E));
}
__device__ __forceinline__ float softplus_f(float v) {
  return log1pf(expf(v));
}

// s_p layout: [0..8]=sp1 [9..17]=sp2 [18..26]=sp3 [27..29]=sp0 [30..32]=sp4
//             [33..35]=b0 [36..38]=b1 [39..41]=b2 [42..44]=b3 [45]=b4
//             [46..48]=tf0 [49..51]=tf1 [52..54]=tf2 [55..57]=tf3
__device__ __forceinline__ float mlp_path(float v, const float* P) {
  float t, a0, a1, a2, d0, d1, d2;
  t = fmaf(P[27], v, P[33]); a0 = fmaf(P[46], fast_tanh(t), t);
  t = fmaf(P[28], v, P[34]); a1 = fmaf(P[47], fast_tanh(t), t);
  t = fmaf(P[29], v, P[35]); a2 = fmaf(P[48], fast_tanh(t), t);

  t = fmaf(P[2], a2, fmaf(P[1], a1, fmaf(P[0], a0, P[36]))); d0 = fmaf(P[49], fast_tanh(t), t);
  t = fmaf(P[5], a2, fmaf(P[4], a1, fmaf(P[3], a0, P[37]))); d1 = fmaf(P[50], fast_tanh(t), t);
  t = fmaf(P[8], a2, fmaf(P[7], a1, fmaf(P[6], a0, P[38]))); d2 = fmaf(P[51], fast_tanh(t), t);

  t = fmaf(P[11], d2, fmaf(P[10], d1, fmaf(P[9],  d0, P[39]))); a0 = fmaf(P[52], fast_tanh(t), t);
  t = fmaf(P[14], d2, fmaf(P[13], d1, fmaf(P[12], d0, P[40]))); a1 = fmaf(P[53], fast_tanh(t), t);
  t = fmaf(P[17], d2, fmaf(P[16], d1, fmaf(P[15], d0, P[41]))); a2 = fmaf(P[54], fast_tanh(t), t);

  t = fmaf(P[20], a2, fmaf(P[19], a1, fmaf(P[18], a0, P[42]))); d0 = fmaf(P[55], fast_tanh(t), t);
  t = fmaf(P[23], a2, fmaf(P[22], a1, fmaf(P[21], a0, P[43]))); d1 = fmaf(P[56], fast_tanh(t), t);
  t = fmaf(P[26], a2, fmaf(P[25], a1, fmaf(P[24], a0, P[44]))); d2 = fmaf(P[57], fast_tanh(t), t);

  return fmaf(P[32], d2, fmaf(P[31], d1, fmaf(P[30], d0, P[45])));
}

// Shared param/table loader (256 threads cooperate). Returns after __syncthreads.
__device__ __forceinline__ void load_tables(
    int t, int c,
    const float* __restrict__ sos_w, const float* __restrict__ sos_b,
    const float* __restrict__ m0, const float* __restrict__ m1,
    const float* __restrict__ m2, const float* __restrict__ m3,
    const float* __restrict__ m4,
    const float* __restrict__ c0, const float* __restrict__ c1,
    const float* __restrict__ c2, const float* __restrict__ c3,
    const float* __restrict__ c4,
    const float* __restrict__ f0, const float* __restrict__ f1,
    const float* __restrict__ f2, const float* __restrict__ f3,
    float* s_w, float* s_kb, float* s_pw, float* s_p)
{
  if (t < 68) {
    float w = (t < 60) ? sos_w[t] : 0.0f;
    float b = (t < 60) ? sos_b[t] : 0.0f;
    s_w[t]  = w;
    s_kb[t] = KSOS * b;
  }
  if (t >= 64 && t < 128) {
    int i = t - 64;
    float v = (i < 60) ? sos_w[i] : 0.0f;
    float s = v;
    #pragma unroll
    for (int off = 1; off < 64; off <<= 1) {
      float o = __shfl_up(s, off, 64);
      if (i >= off) s += o;
    }
    if (i <= 60) s_pw[i] = s - v;
  }
  {
    int p = t - 128;
    if (p >= 0 && p < 58) {
      float val;
      if      (p <  9) val = softplus_f(m1[c*9 +  p      ]);
      else if (p < 18) val = softplus_f(m2[c*9 + (p -  9)]);
      else if (p < 27) val = softplus_f(m3[c*9 + (p - 18)]);
      else if (p < 30) val = softplus_f(m0[c*3 + (p - 27)]);
      else if (p < 33) val = softplus_f(m4[c*3 + (p - 30)]);
      else if (p < 36) val = c0[c*3 + (p - 33)];
      else if (p < 39) val = c1[c*3 + (p - 36)];
      else if (p < 42) val = c2[c*3 + (p - 39)];
      else if (p < 45) val = c3[c*3 + (p - 42)];
      else if (p < 46) val = c4[c];
      else if (p < 49) val = tanhf(f0[c*3 + (p - 46)]);
      else if (p < 52) val = tanhf(f1[c*3 + (p - 49)]);
      else if (p < 55) val = tanhf(f2[c*3 + (p - 52)]);
      else             val = tanhf(f3[c*3 + (p - 55)]);
      s_p[p] = val;
    }
  }
  __syncthreads();
}

// Full per-value evaluation: yq = SoS(x), lik = g_c(yq)
__device__ __forceinline__ void eval_point(
    float xx, const float* s_w, const float* s_kb, const float* s_pw,
    const float* P, float* yq_out, float* lik_out)
{
  // SoS window of 6 steps starting at b >= x-0.68; head err ~1.2e-6*w/step
  float kf = ceilf((xx + 9.32f) * INV_D);
  int k = (int)kf;
  k = max(0, min(60, k));
  float acc = s_pw[k];
  float kx  = KSOS * xx;
  #pragma unroll
  for (int i = 0; i < 6; ++i) {
    float z = s_kb[k + i] - kx;
    acc = fmaf(s_w[k + i], rcp_f(1.0f + exp2_f(z)), acc);
  }
  float yq = acc - 10.0f;

  float lo = mlp_path(yq - 0.5f, P);
  float up = mlp_path(yq + 0.5f, P);
  float lu = lo + up;
  float sg = (lu > 0.0f) ? -1.0f : ((lu < 0.0f) ? 1.0f : 0.0f);
  float lik = fabsf(fast_sigmoid(sg * up) - fast_sigmoid(sg * lo));
  *yq_out  = yq;
  *lik_out = fmaxf(lik, 1e-9f);
}

// ---------------- Kernel 1: build per-channel LUT of (y_hat, lik) ----------
__global__ __launch_bounds__(256)
void eb_lut_build(const float* __restrict__ sos_w, const float* __restrict__ sos_b,
                  const float* __restrict__ m0, const float* __restrict__ m1,
                  const float* __restrict__ m2, const float* __restrict__ m3,
                  const float* __restrict__ m4,
                  const float* __restrict__ c0, const float* __restrict__ c1,
                  const float* __restrict__ c2, const float* __restrict__ c3,
                  const float* __restrict__ c4,
                  const float* __restrict__ f0, const float* __restrict__ f1,
                  const float* __restrict__ f2, const float* __restrict__ f3,
                  float2* __restrict__ lut)
{
  __shared__ float s_w[68], s_kb[68], s_pw[64], s_p[58];
  const int t = threadIdx.x;
  const int c = blockIdx.x / CHUNKS_;
  const int chunk = blockIdx.x % CHUNKS_;

  load_tables(t, c, sos_w, sos_b, m0, m1, m2, m3, m4,
              c0, c1, c2, c3, c4, f0, f1, f2, f3, s_w, s_kb, s_pw, s_p);

  float P[58];
  #pragma unroll
  for (int i = 0; i < 58; ++i) P[i] = s_p[i];

  float2* dst = lut + (size_t)c * LUT_L + chunk * EPB_;
  #pragma unroll
  for (int r = 0; r < EPB_ / 256; ++r) {
    int idx = chunk * EPB_ + r * 256 + t;
    float xg = LUT_X0 + (float)idx * LUT_H;
    float yq, lik;
    eval_point(xg, s_w, s_kb, s_pw, P, &yq, &lik);
    dst[r * 256 + t] = make_float2(yq, lik);
  }
}

// ---------------- Kernel 2: gather + lerp --------------------------------
__global__ __launch_bounds__(256)
void eb_interp(const float* __restrict__ x, const float2* __restrict__ lut,
               float* __restrict__ out)
{
  __shared__ float4 s_l4[LUT_L / 2];   // (y,l,y,l) pairs; 16 KB
  const int t     = threadIdx.x;
  const int plane = blockIdx.x;
  const int c     = plane % C_CH;

  const float4* src = reinterpret_cast<const float4*>(lut + (size_t)c * LUT_L);
  #pragma unroll
  for (int i = 0; i < LUT_L / 2 / 256; ++i)
    s_l4[t + 256 * i] = src[t + 256 * i];
  __syncthreads();
  const float2* s_l = reinterpret_cast<const float2*>(s_l4);

  const int base = plane * HW_;
  float4 xv = reinterpret_cast<const float4*>(x + base)[t];
  float xs[4] = {xv.x, xv.y, xv.z, xv.w};
  float ys[4], ls[4];

  #pragma unroll
  for (int e = 0; e < 4; ++e) {
    float xx = fminf(fmaxf(xs[e], -12.0f), 12.0f);
    float u  = (xx + 12.0f) * LUT_IH;
    int   i  = (int)u;
    i = min(i, LUT_L - 2);
    float fr = u - (float)i;
    float2 a = s_l[i];
    float2 b = s_l[i + 1];
    ys[e] = fmaf(fr, b.x - a.x, a.x);
    ls[e] = fmaf(fr, b.y - a.y, a.y);
  }

  reinterpret_cast<float4*>(out + base)[t]          = make_float4(ys[0], ys[1], ys[2], ys[3]);
  reinterpret_cast<float4*>(out + TOTAL_ + base)[t] = make_float4(ls[0], ls[1], ls[2], ls[3]);
}

// ---------------- Fallback: round-0 direct kernel ------------------------
__global__ __launch_bounds__(256)
void eb_sos_kernel(const float* __restrict__ x,
                   const float* __restrict__ sos_w, const float* __restrict__ sos_b,
                   const float* __restrict__ m0, const float* __restrict__ m1,
                   const float* __restrict__ m2, const float* __restrict__ m3,
                   const float* __restrict__ m4,
                   const float* __restrict__ c0, const float* __restrict__ c1,
                   const float* __restrict__ c2, const float* __restrict__ c3,
                   const float* __restrict__ c4,
                   const float* __restrict__ f0, const float* __restrict__ f1,
                   const float* __restrict__ f2, const float* __restrict__ f3,
                   float* __restrict__ out)
{
  __shared__ float s_w[68], s_kb[68], s_pw[64], s_p[58];
  const int t     = threadIdx.x;
  const int plane = blockIdx.x;
  const int c     = plane % C_CH;

  load_tables(t, c, sos_w, sos_b, m0, m1, m2, m3, m4,
              c0, c1, c2, c3, c4, f0, f1, f2, f3, s_w, s_kb, s_pw, s_p);

  float P[58];
  #pragma unroll
  for (int i = 0; i < 58; ++i) P[i] = s_p[i];

  const int base = plane * HW_;
  float4 xv = reinterpret_cast<const float4*>(x + base)[t];
  float xs[4] = {xv.x, xv.y, xv.z, xv.w};
  float ys[4], ls[4];

  #pragma unroll
  for (int e = 0; e < 4; ++e)
    eval_point(xs[e], s_w, s_kb, s_pw, P, &ys[e], &ls[e]);

  reinterpret_cast<float4*>(out + base)[t]          = make_float4(ys[0], ys[1], ys[2], ys[3]);
  reinterpret_cast<float4*>(out + TOTAL_ + base)[t] = make_float4(ls[0], ls[1], ls[2], ls[3]);
}

extern "C" void kernel_launch(void* const* d_in, const int* in_sizes, int n_in,
                              void* d_out, int out_size, void* d_ws, size_t ws_size,
                              hipStream_t stream) {
  const float* x  = (const float*)d_in[0];
  const float* sw = (const float*)d_in[1];
  const float* sb = (const float*)d_in[2];
  const float *M[5], *B[5], *F[4];

  if (n_in >= 17 && in_sizes[4] == 1728) {
    for (int i = 0; i < 5; ++i) M[i] = (const float*)d_in[3 + i];
    for (int i = 0; i < 5; ++i) B[i] = (const float*)d_in[8 + i];
    for (int i = 0; i < 4; ++i) F[i] = (const float*)d_in[13 + i];
  } else {
    M[0] = (const float*)d_in[3];  B[0] = (const float*)d_in[4];  F[0] = (const float*)d_in[5];
    M[1] = (const float*)d_in[6];  B[1] = (const float*)d_in[7];  F[1] = (const float*)d_in[8];
    M[2] = (const float*)d_in[9];  B[2] = (const float*)d_in[10]; F[2] = (const float*)d_in[11];
    M[3] = (const float*)d_in[12]; B[3] = (const float*)d_in[13]; F[3] = (const float*)d_in[14];
    M[4] = (const float*)d_in[15]; B[4] = (const float*)d_in[16];
  }

  const size_t lut_bytes = (size_t)C_CH * LUT_L * sizeof(float2);  // 3 MiB

  if (ws_size >= lut_bytes) {
    float2* lut = (float2*)d_ws;
    hipLaunchKernelGGL(eb_lut_build, dim3(C_CH * CHUNKS_), dim3(256), 0, stream,
                       sw, sb, M[0], M[1], M[2], M[3], M[4],
                       B[0], B[1], B[2], B[3], B[4],
                       F[0], F[1], F[2], F[3], lut);
    hipLaunchKernelGGL(eb_interp, dim3(NPLANE), dim3(256), 0, stream,
                       x, lut, (float*)d_out);
  } else {
    hipLaunchKernelGGL(eb_sos_kernel, dim3(NPLANE), dim3(256), 0, stream,
                       x, sw, sb, M[0], M[1], M[2], M[3], M[4],
                       B[0], B[1], B[2], B[3], B[4],
                       F[0], F[1], F[2], F[3], (float*)d_out);
  }
}

// Round 3
// 17.975 us; speedup vs baseline: 1.3625x; 1.0809x over previous
//
#include <hip/hip_runtime.h>
#include <math.h>

#define C_CH    192
#define HW_     1024
#define NPLANE  1536           // 8*192 planes of H*W=1024
#define TOTAL_  1572864        // 8*192*32*32

#define LOG2E   1.4426950408889634f
#define KSOS    28.853900817779268f   /* 2*BETA*log2(e) = 20*log2(e) */
#define INV_D   2.95f                 /* 59/20: inverse spacing of sos_b grid */

#define LUT_L   512
#define LUT_X0  (-10.72f)
#define LUT_SPAN 21.44f
#define LUT_H   (LUT_SPAN / (LUT_L - 1))
#define LUT_IH  ((LUT_L - 1) / LUT_SPAN)

__device__ __forceinline__ float rcp_f(float v)  { return __builtin_amdgcn_rcpf(v); }
__device__ __forceinline__ float exp2_f(float v) { return __builtin_amdgcn_exp2f(v); }

__device__ __forceinline__ float fast_tanh(float z) {
  float e = exp2_f(z * (2.0f * LOG2E));
  return 1.0f - 2.0f * rcp_f(e + 1.0f);
}
__device__ __forceinline__ float fast_sigmoid(float z) {
  return rcp_f(1.0f + exp2_f(-z * LOG2E));
}
__device__ __forceinline__ float softplus_f(float v) {
  return log1pf(expf(v));
}

// s_p layout: [0..8]=sp1 [9..17]=sp2 [18..26]=sp3 [27..29]=sp0 [30..32]=sp4
//             [33..35]=b0 [36..38]=b1 [39..41]=b2 [42..44]=b3 [45]=b4
//             [46..48]=tf0 [49..51]=tf1 [52..54]=tf2 [55..57]=tf3
__device__ __forceinline__ float mlp_path(float v, const float* P) {
  float t, a0, a1, a2, d0, d1, d2;
  t = fmaf(P[27], v, P[33]); a0 = fmaf(P[46], fast_tanh(t), t);
  t = fmaf(P[28], v, P[34]); a1 = fmaf(P[47], fast_tanh(t), t);
  t = fmaf(P[29], v, P[35]); a2 = fmaf(P[48], fast_tanh(t), t);

  t = fmaf(P[2], a2, fmaf(P[1], a1, fmaf(P[0], a0, P[36]))); d0 = fmaf(P[49], fast_tanh(t), t);
  t = fmaf(P[5], a2, fmaf(P[4], a1, fmaf(P[3], a0, P[37]))); d1 = fmaf(P[50], fast_tanh(t), t);
  t = fmaf(P[8], a2, fmaf(P[7], a1, fmaf(P[6], a0, P[38]))); d2 = fmaf(P[51], fast_tanh(t), t);

  t = fmaf(P[11], d2, fmaf(P[10], d1, fmaf(P[9],  d0, P[39]))); a0 = fmaf(P[52], fast_tanh(t), t);
  t = fmaf(P[14], d2, fmaf(P[13], d1, fmaf(P[12], d0, P[40]))); a1 = fmaf(P[53], fast_tanh(t), t);
  t = fmaf(P[17], d2, fmaf(P[16], d1, fmaf(P[15], d0, P[41]))); a2 = fmaf(P[54], fast_tanh(t), t);

  t = fmaf(P[20], a2, fmaf(P[19], a1, fmaf(P[18], a0, P[42]))); d0 = fmaf(P[55], fast_tanh(t), t);
  t = fmaf(P[23], a2, fmaf(P[22], a1, fmaf(P[21], a0, P[43]))); d1 = fmaf(P[56], fast_tanh(t), t);
  t = fmaf(P[26], a2, fmaf(P[25], a1, fmaf(P[24], a0, P[44]))); d2 = fmaf(P[57], fast_tanh(t), t);

  return fmaf(P[32], d2, fmaf(P[31], d1, fmaf(P[30], d0, P[45])));
}

__device__ __forceinline__ void load_tables(
    int t, int c,
    const float* __restrict__ sos_w, const float* __restrict__ sos_b,
    const float* __restrict__ m0, const float* __restrict__ m1,
    const float* __restrict__ m2, const float* __restrict__ m3,
    const float* __restrict__ m4,
    const float* __restrict__ c0, const float* __restrict__ c1,
    const float* __restrict__ c2, const float* __restrict__ c3,
    const float* __restrict__ c4,
    const float* __restrict__ f0, const float* __restrict__ f1,
    const float* __restrict__ f2, const float* __restrict__ f3,
    float* s_w, float* s_kb, float* s_pw, float* s_p)
{
  if (t < 68) {
    float w = (t < 60) ? sos_w[t] : 0.0f;
    float b = (t < 60) ? sos_b[t] : 0.0f;
    s_w[t]  = w;
    s_kb[t] = KSOS * b;
  }
  if (t >= 64 && t < 128) {
    int i = t - 64;
    float v = (i < 60) ? sos_w[i] : 0.0f;
    float s = v;
    #pragma unroll
    for (int off = 1; off < 64; off <<= 1) {
      float o = __shfl_up(s, off, 64);
      if (i >= off) s += o;
    }
    if (i <= 60) s_pw[i] = s - v;        // exclusive prefix: sum_{j<i} w_j
  }
  {
    int p = t - 128;
    if (p >= 0 && p < 58) {
      float val;
      if      (p <  9) val = softplus_f(m1[c*9 +  p      ]);
      else if (p < 18) val = softplus_f(m2[c*9 + (p -  9)]);
      else if (p < 27) val = softplus_f(m3[c*9 + (p - 18)]);
      else if (p < 30) val = softplus_f(m0[c*3 + (p - 27)]);
      else if (p < 33) val = softplus_f(m4[c*3 + (p - 30)]);
      else if (p < 36) val = c0[c*3 + (p - 33)];
      else if (p < 39) val = c1[c*3 + (p - 36)];
      else if (p < 42) val = c2[c*3 + (p - 39)];
      else if (p < 45) val = c3[c*3 + (p - 42)];
      else if (p < 46) val = c4[c];
      else if (p < 49) val = tanhf(f0[c*3 + (p - 46)]);
      else if (p < 52) val = tanhf(f1[c*3 + (p - 49)]);
      else if (p < 55) val = tanhf(f2[c*3 + (p - 52)]);
      else             val = tanhf(f3[c*3 + (p - 55)]);
      s_p[p] = val;
    }
  }
  __syncthreads();
}

__device__ __forceinline__ void eval_point(
    float xx, const float* s_w, const float* s_kb, const float* s_pw,
    const float* P, float* yq_out, float* lik_out)
{
  // SoS window of 6 steps starting at first b >= x-0.68;
  // skipped-head error <= 2.4e-5, tail < 2e-12.
  float kf = ceilf((xx + 9.32f) * INV_D);
  int k = (int)kf;
  k = max(0, min(60, k));
  float acc = s_pw[k];
  float kx  = KSOS * xx;
  #pragma unroll
  for (int i = 0; i < 6; ++i) {
    float z = s_kb[k + i] - kx;
    acc = fmaf(s_w[k + i], rcp_f(1.0f + exp2_f(z)), acc);
  }
  float yq = acc - 10.0f;

  float lo = mlp_path(yq - 0.5f, P);
  float up = mlp_path(yq + 0.5f, P);
  float lu = lo + up;
  float sg = (lu > 0.0f) ? -1.0f : ((lu < 0.0f) ? 1.0f : 0.0f);
  float lik = fabsf(fast_sigmoid(sg * up) - fast_sigmoid(sg * lo));
  *yq_out  = yq;
  *lik_out = fmaxf(lik, 1e-9f);
}

// ---------------- Fused kernel: per-block LUT build + gather/lerp ---------
__global__ __launch_bounds__(256)
void eb_fused(const float* __restrict__ x,
              const float* __restrict__ sos_w, const float* __restrict__ sos_b,
              const float* __restrict__ m0, const float* __restrict__ m1,
              const float* __restrict__ m2, const float* __restrict__ m3,
              const float* __restrict__ m4,
              const float* __restrict__ c0, const float* __restrict__ c1,
              const float* __restrict__ c2, const float* __restrict__ c3,
              const float* __restrict__ c4,
              const float* __restrict__ f0, const float* __restrict__ f1,
              const float* __restrict__ f2, const float* __restrict__ f3,
              float* __restrict__ out)
{
  __shared__ float s_w[68], s_kb[68], s_pw[64], s_p[58];
  __shared__ float s_y[LUT_L], s_l[LUT_L];

  const int t     = threadIdx.x;
  const int plane = blockIdx.x;          // n*C + c
  const int c     = plane % C_CH;

  // start the input load early; it is independent of the LUT build
  const int base = plane * HW_;
  float4 xv = reinterpret_cast<const float4*>(x + base)[t];

  load_tables(t, c, sos_w, sos_b, m0, m1, m2, m3, m4,
              c0, c1, c2, c3, c4, f0, f1, f2, f3, s_w, s_kb, s_pw, s_p);

  float P[58];
  #pragma unroll
  for (int i = 0; i < 58; ++i) P[i] = s_p[i];

  // build the 512-entry per-channel LUT: 2 points per thread
  #pragma unroll
  for (int r = 0; r < LUT_L / 256; ++r) {
    int idx = t + 256 * r;
    float xg = LUT_X0 + (float)idx * LUT_H;
    float yq, lik;
    eval_point(xg, s_w, s_kb, s_pw, P, &yq, &lik);
    s_y[idx] = yq;
    s_l[idx] = lik;
  }
  __syncthreads();

  float xs[4] = {xv.x, xv.y, xv.z, xv.w};
  float ys[4], ls[4];
  #pragma unroll
  for (int e = 0; e < 4; ++e) {
    float xx = fminf(fmaxf(xs[e], LUT_X0), LUT_X0 + LUT_SPAN);
    float u  = (xx - LUT_X0) * LUT_IH;
    int   i  = (int)u;
    i = min(i, LUT_L - 2);
    float fr = u - (float)i;
    float y0 = s_y[i], y1 = s_y[i + 1];
    float l0 = s_l[i], l1 = s_l[i + 1];
    ys[e] = fmaf(fr, y1 - y0, y0);
    ls[e] = fmaf(fr, l1 - l0, l0);
  }

  reinterpret_cast<float4*>(out + base)[t]          = make_float4(ys[0], ys[1], ys[2], ys[3]);
  reinterpret_cast<float4*>(out + TOTAL_ + base)[t] = make_float4(ls[0], ls[1], ls[2], ls[3]);
}

extern "C" void kernel_launch(void* const* d_in, const int* in_sizes, int n_in,
                              void* d_out, int out_size, void* d_ws, size_t ws_size,
                              hipStream_t stream) {
  const float* x  = (const float*)d_in[0];
  const float* sw = (const float*)d_in[1];
  const float* sb = (const float*)d_in[2];
  const float *M[5], *B[5], *F[4];

  if (n_in >= 17 && in_sizes[4] == 1728) {
    // reference-signature order: m0..m4, c0..c4, f0..f3
    for (int i = 0; i < 5; ++i) M[i] = (const float*)d_in[3 + i];
    for (int i = 0; i < 5; ++i) B[i] = (const float*)d_in[8 + i];
    for (int i = 0; i < 4; ++i) F[i] = (const float*)d_in[13 + i];
  } else {
    // setup_inputs() dict order: m0,c0,f0, m1,c1,f1, ..., m4,c4
    M[0] = (const float*)d_in[3];  B[0] = (const float*)d_in[4];  F[0] = (const float*)d_in[5];
    M[1] = (const float*)d_in[6];  B[1] = (const float*)d_in[7];  F[1] = (const float*)d_in[8];
    M[2] = (const float*)d_in[9];  B[2] = (const float*)d_in[10]; F[2] = (const float*)d_in[11];
    M[3] = (const float*)d_in[12]; B[3] = (const float*)d_in[13]; F[3] = (const float*)d_in[14];
    M[4] = (const float*)d_in[15]; B[4] = (const float*)d_in[16];
  }

  hipLaunchKernelGGL(eb_fused, dim3(NPLANE), dim3(256), 0, stream,
                     x, sw, sb,
                     M[0], M[1], M[2], M[3], M[4],
                     B[0], B[1], B[2], B[3], B[4],
                     F[0], F[1], F[2], F[3],
                     (float*)d_out);
}

// Round 4
// 14.330 us; speedup vs baseline: 1.7091x; 1.2544x over previous
//
#include <hip/hip_runtime.h>
#include <math.h>

#define C_CH    192
#define HW_     1024
#define NPLANE  1536           // 8*192 planes of H*W=1024
#define TOTAL_  1572864        // 8*192*32*32
#define PPB     2              // planes per block (same channel)
#define NBLK    (NPLANE / PPB) // 768

#define LOG2E   1.4426950408889634f
#define KSOS    28.853900817779268f   /* 2*BETA*log2(e) = 20*log2(e) */
#define INV_D   2.95f                 /* 59/20: inverse spacing of sos_b grid */

#define LUT_L   512
#define LUT_X0  (-10.72f)
#define LUT_SPAN 21.44f
#define LUT_H   (LUT_SPAN / (LUT_L - 1))
#define LUT_IH  ((LUT_L - 1) / LUT_SPAN)

__device__ __forceinline__ float rcp_f(float v)  { return __builtin_amdgcn_rcpf(v); }
__device__ __forceinline__ float exp2_f(float v) { return __builtin_amdgcn_exp2f(v); }

__device__ __forceinline__ float fast_tanh(float z) {
  float e = exp2_f(z * (2.0f * LOG2E));
  return 1.0f - 2.0f * rcp_f(e + 1.0f);
}
__device__ __forceinline__ float fast_sigmoid(float z) {
  return rcp_f(1.0f + exp2_f(-z * LOG2E));
}
__device__ __forceinline__ float softplus_f(float v) {
  return log1pf(expf(v));
}

// s_p layout: [0..8]=sp1 [9..17]=sp2 [18..26]=sp3 [27..29]=sp0 [30..32]=sp4
//             [33..35]=b0 [36..38]=b1 [39..41]=b2 [42..44]=b3 [45]=b4
//             [46..48]=tf0 [49..51]=tf1 [52..54]=tf2 [55..57]=tf3
__device__ __forceinline__ float mlp_full(float v, const float* P) {
  float t, a0, a1, a2, d0, d1, d2;
  t = fmaf(P[27], v, P[33]); a0 = fmaf(P[46], fast_tanh(t), t);
  t = fmaf(P[28], v, P[34]); a1 = fmaf(P[47], fast_tanh(t), t);
  t = fmaf(P[29], v, P[35]); a2 = fmaf(P[48], fast_tanh(t), t);

  t = fmaf(P[2], a2, fmaf(P[1], a1, fmaf(P[0], a0, P[36]))); d0 = fmaf(P[49], fast_tanh(t), t);
  t = fmaf(P[5], a2, fmaf(P[4], a1, fmaf(P[3], a0, P[37]))); d1 = fmaf(P[50], fast_tanh(t), t);
  t = fmaf(P[8], a2, fmaf(P[7], a1, fmaf(P[6], a0, P[38]))); d2 = fmaf(P[51], fast_tanh(t), t);

  t = fmaf(P[11], d2, fmaf(P[10], d1, fmaf(P[9],  d0, P[39]))); a0 = fmaf(P[52], fast_tanh(t), t);
  t = fmaf(P[14], d2, fmaf(P[13], d1, fmaf(P[12], d0, P[40]))); a1 = fmaf(P[53], fast_tanh(t), t);
  t = fmaf(P[17], d2, fmaf(P[16], d1, fmaf(P[15], d0, P[41]))); a2 = fmaf(P[54], fast_tanh(t), t);

  t = fmaf(P[20], a2, fmaf(P[19], a1, fmaf(P[18], a0, P[42]))); d0 = fmaf(P[55], fast_tanh(t), t);
  t = fmaf(P[23], a2, fmaf(P[22], a1, fmaf(P[21], a0, P[43]))); d1 = fmaf(P[56], fast_tanh(t), t);
  t = fmaf(P[26], a2, fmaf(P[25], a1, fmaf(P[24], a0, P[44]))); d2 = fmaf(P[57], fast_tanh(t), t);

  return fmaf(P[32], d2, fmaf(P[31], d1, fmaf(P[30], d0, P[45])));
}

// factors==0 path: every "logits + tanh(f)*tanh(logits)" collapses to identity.
__device__ __forceinline__ float mlp_fast(float v, const float* P) {
  float a0, a1, a2, d0, d1, d2;
  a0 = fmaf(P[27], v, P[33]);
  a1 = fmaf(P[28], v, P[34]);
  a2 = fmaf(P[29], v, P[35]);

  d0 = fmaf(P[2], a2, fmaf(P[1], a1, fmaf(P[0], a0, P[36])));
  d1 = fmaf(P[5], a2, fmaf(P[4], a1, fmaf(P[3], a0, P[37])));
  d2 = fmaf(P[8], a2, fmaf(P[7], a1, fmaf(P[6], a0, P[38])));

  a0 = fmaf(P[11], d2, fmaf(P[10], d1, fmaf(P[9],  d0, P[39])));
  a1 = fmaf(P[14], d2, fmaf(P[13], d1, fmaf(P[12], d0, P[40])));
  a2 = fmaf(P[17], d2, fmaf(P[16], d1, fmaf(P[15], d0, P[41])));

  d0 = fmaf(P[20], a2, fmaf(P[19], a1, fmaf(P[18], a0, P[42])));
  d1 = fmaf(P[23], a2, fmaf(P[22], a1, fmaf(P[21], a0, P[43])));
  d2 = fmaf(P[26], a2, fmaf(P[25], a1, fmaf(P[24], a0, P[44])));

  return fmaf(P[32], d2, fmaf(P[31], d1, fmaf(P[30], d0, P[45])));
}

__device__ __forceinline__ void load_tables(
    int t, int c,
    const float* __restrict__ sos_w, const float* __restrict__ sos_b,
    const float* __restrict__ m0, const float* __restrict__ m1,
    const float* __restrict__ m2, const float* __restrict__ m3,
    const float* __restrict__ m4,
    const float* __restrict__ c0, const float* __restrict__ c1,
    const float* __restrict__ c2, const float* __restrict__ c3,
    const float* __restrict__ c4,
    const float* __restrict__ f0, const float* __restrict__ f1,
    const float* __restrict__ f2, const float* __restrict__ f3,
    float* s_w, float* s_kb, float* s_pw, float* s_p)
{
  if (t < 68) {
    float w = (t < 60) ? sos_w[t] : 0.0f;
    float b = (t < 60) ? sos_b[t] : 0.0f;
    s_w[t]  = w;
    s_kb[t] = KSOS * b;
  }
  if (t >= 64 && t < 128) {
    int i = t - 64;
    float v = (i < 60) ? sos_w[i] : 0.0f;
    float s = v;
    #pragma unroll
    for (int off = 1; off < 64; off <<= 1) {
      float o = __shfl_up(s, off, 64);
      if (i >= off) s += o;
    }
    if (i <= 60) s_pw[i] = s - v;        // exclusive prefix: sum_{j<i} w_j
  }
  {
    int p = t - 128;
    if (p >= 0 && p < 58) {
      float val;
      if      (p <  9) val = softplus_f(m1[c*9 +  p      ]);
      else if (p < 18) val = softplus_f(m2[c*9 + (p -  9)]);
      else if (p < 27) val = softplus_f(m3[c*9 + (p - 18)]);
      else if (p < 30) val = softplus_f(m0[c*3 + (p - 27)]);
      else if (p < 33) val = softplus_f(m4[c*3 + (p - 30)]);
      else if (p < 36) val = c0[c*3 + (p - 33)];
      else if (p < 39) val = c1[c*3 + (p - 36)];
      else if (p < 42) val = c2[c*3 + (p - 39)];
      else if (p < 45) val = c3[c*3 + (p - 42)];
      else if (p < 46) val = c4[c];
      else if (p < 49) val = tanhf(f0[c*3 + (p - 46)]);
      else if (p < 52) val = tanhf(f1[c*3 + (p - 49)]);
      else if (p < 55) val = tanhf(f2[c*3 + (p - 52)]);
      else             val = tanhf(f3[c*3 + (p - 55)]);
      s_p[p] = val;
    }
  }
  __syncthreads();
}

// SoS staircase: windowed sum of sigmoids + exclusive prefix of saturated steps
__device__ __forceinline__ float sos_eval(
    float xx, const float* s_w, const float* s_kb, const float* s_pw)
{
  float kf = ceilf((xx + 9.32f) * INV_D);
  int k = (int)kf;
  k = max(0, min(60, k));
  float acc = s_pw[k];
  float kx  = KSOS * xx;
  #pragma unroll
  for (int i = 0; i < 6; ++i) {
    float z = s_kb[k + i] - kx;
    acc = fmaf(s_w[k + i], rcp_f(1.0f + exp2_f(z)), acc);
  }
  return acc - 10.0f;
}

template <bool FAST>
__device__ __forceinline__ float lik_from_y(float yq, const float* P) {
  float lo = FAST ? mlp_fast(yq - 0.5f, P) : mlp_full(yq - 0.5f, P);
  float up = FAST ? mlp_fast(yq + 0.5f, P) : mlp_full(yq + 0.5f, P);
  float lu = lo + up;
  float sg = (lu > 0.0f) ? -1.0f : ((lu < 0.0f) ? 1.0f : 0.0f);
  float lik = fabsf(fast_sigmoid(sg * up) - fast_sigmoid(sg * lo));
  return fmaxf(lik, 1e-9f);
}

// ---------------- Fused kernel: per-block LUT build + gather/lerp ---------
__global__ __launch_bounds__(256)
void eb_fused(const float* __restrict__ x,
              const float* __restrict__ sos_w, const float* __restrict__ sos_b,
              const float* __restrict__ m0, const float* __restrict__ m1,
              const float* __restrict__ m2, const float* __restrict__ m3,
              const float* __restrict__ m4,
              const float* __restrict__ c0, const float* __restrict__ c1,
              const float* __restrict__ c2, const float* __restrict__ c3,
              const float* __restrict__ c4,
              const float* __restrict__ f0, const float* __restrict__ f1,
              const float* __restrict__ f2, const float* __restrict__ f3,
              float* __restrict__ out)
{
  __shared__ float s_w[68], s_kb[68], s_pw[64], s_p[58];
  __shared__ float s_y[LUT_L], s_l[LUT_L];

  const int t  = threadIdx.x;
  const int c  = blockIdx.x % C_CH;      // channel
  const int g  = blockIdx.x / C_CH;      // plane-pair index 0..3
  const int p0 = (2 * g)     * C_CH + c;
  const int p1 = (2 * g + 1) * C_CH + c;

  // start the input loads early; independent of the LUT build
  const int base0 = p0 * HW_;
  const int base1 = p1 * HW_;
  float4 xv0 = reinterpret_cast<const float4*>(x + base0)[t];
  float4 xv1 = reinterpret_cast<const float4*>(x + base1)[t];

  load_tables(t, c, sos_w, sos_b, m0, m1, m2, m3, m4,
              c0, c1, c2, c3, c4, f0, f1, f2, f3, s_w, s_kb, s_pw, s_p);

  float P[58];
  #pragma unroll
  for (int i = 0; i < 58; ++i) P[i] = s_p[i];

  // wave-uniform runtime check: all factor-tanh values zero?
  bool nofac = true;
  #pragma unroll
  for (int i = 46; i < 58; ++i) nofac &= (P[i] == 0.0f);

  // build the 512-entry per-channel LUT: 2 points per thread
  if (nofac) {
    #pragma unroll
    for (int r = 0; r < LUT_L / 256; ++r) {
      int idx = t + 256 * r;
      float xg = LUT_X0 + (float)idx * LUT_H;
      float yq = sos_eval(xg, s_w, s_kb, s_pw);
      s_y[idx] = yq;
      s_l[idx] = lik_from_y<true>(yq, P);
    }
  } else {
    #pragma unroll
    for (int r = 0; r < LUT_L / 256; ++r) {
      int idx = t + 256 * r;
      float xg = LUT_X0 + (float)idx * LUT_H;
      float yq = sos_eval(xg, s_w, s_kb, s_pw);
      s_y[idx] = yq;
      s_l[idx] = lik_from_y<false>(yq, P);
    }
  }
  __syncthreads();

  // interp both planes
  float4 xvs[PPB] = {xv0, xv1};
  int bases[PPB]  = {base0, base1};
  #pragma unroll
  for (int pl = 0; pl < PPB; ++pl) {
    float xs[4] = {xvs[pl].x, xvs[pl].y, xvs[pl].z, xvs[pl].w};
    float ys[4], ls[4];
    #pragma unroll
    for (int e = 0; e < 4; ++e) {
      float xx = fminf(fmaxf(xs[e], LUT_X0), LUT_X0 + LUT_SPAN);
      float u  = (xx - LUT_X0) * LUT_IH;
      int   i  = (int)u;
      i = min(i, LUT_L - 2);
      float fr = u - (float)i;
      float y0 = s_y[i], y1 = s_y[i + 1];
      float l0 = s_l[i], l1 = s_l[i + 1];
      ys[e] = fmaf(fr, y1 - y0, y0);
      ls[e] = fmaf(fr, l1 - l0, l0);
    }
    reinterpret_cast<float4*>(out + bases[pl])[t]          = make_float4(ys[0], ys[1], ys[2], ys[3]);
    reinterpret_cast<float4*>(out + TOTAL_ + bases[pl])[t] = make_float4(ls[0], ls[1], ls[2], ls[3]);
  }
}

extern "C" void kernel_launch(void* const* d_in, const int* in_sizes, int n_in,
                              void* d_out, int out_size, void* d_ws, size_t ws_size,
                              hipStream_t stream) {
  const float* x  = (const float*)d_in[0];
  const float* sw = (const float*)d_in[1];
  const float* sb = (const float*)d_in[2];
  const float *M[5], *B[5], *F[4];

  if (n_in >= 17 && in_sizes[4] == 1728) {
    // reference-signature order: m0..m4, c0..c4, f0..f3
    for (int i = 0; i < 5; ++i) M[i] = (const float*)d_in[3 + i];
    for (int i = 0; i < 5; ++i) B[i] = (const float*)d_in[8 + i];
    for (int i = 0; i < 4; ++i) F[i] = (const float*)d_in[13 + i];
  } else {
    // setup_inputs() dict order: m0,c0,f0, m1,c1,f1, ..., m4,c4
    M[0] = (const float*)d_in[3];  B[0] = (const float*)d_in[4];  F[0] = (const float*)d_in[5];
    M[1] = (const float*)d_in[6];  B[1] = (const float*)d_in[7];  F[1] = (const float*)d_in[8];
    M[2] = (const float*)d_in[9];  B[2] = (const float*)d_in[10]; F[2] = (const float*)d_in[11];
    M[3] = (const float*)d_in[12]; B[3] = (const float*)d_in[13]; F[3] = (const float*)d_in[14];
    M[4] = (const float*)d_in[15]; B[4] = (const float*)d_in[16];
  }

  hipLaunchKernelGGL(eb_fused, dim3(NBLK), dim3(256), 0, stream,
                     x, sw, sb,
                     M[0], M[1], M[2], M[3], M[4],
                     B[0], B[1], B[2], B[3], B[4],
                     F[0], F[1], F[2], F[3],
                     (float*)d_out);
}